// Round 13
// baseline (59.078 us; speedup 1.0000x reference)
//
#include <hip/hip_runtime.h>
#include <hip/hip_bf16.h>
#include <cmath>

#define CT    1024   // C*T channels
#define PIX   1296   // 36*36 pixels
#define BATCH 16
#define NNEUR 4096
#define HW    36
#define NBINS (HW * HW)
#define NB    8      // neurons per readout block
#define BQ    4      // batches per readout block
#define BCT   (BATCH * CT)   // stride of one pixel in feat

// staging kernel role layout
#define SORT_BLK   1
#define PACK_BLKS  2048                    // 4096*1024 floats / (256 thr * 8)
#define TRAN_BLKS  (41 * 16 * 16)          // 10496
#define STAGE_GRID (SORT_BLK + PACK_BLKS + TRAN_BLKS)

#if defined(__has_builtin)
#  if __has_builtin(__builtin_amdgcn_fdot2_f32_bf16)
#    define HAVE_FDOT2_BF16 1
#  endif
#endif
#ifndef HAVE_FDOT2_BF16
#  define HAVE_FDOT2_BF16 0
#endif

typedef __bf16 bf16x2 __attribute__((ext_vector_type(2)));
__device__ __forceinline__ bf16x2 as_bf16x2(unsigned u) {
    union { unsigned u; bf16x2 v; } cv; cv.u = u; return cv.v;
}
__device__ __forceinline__ unsigned short bfu(float f) {
    __hip_bfloat16 h = __float2bfloat16(f);
    return *reinterpret_cast<unsigned short*>(&h);
}
__device__ __forceinline__ float bflo(unsigned u) { return __uint_as_float(u << 16); }
__device__ __forceinline__ float bfhi(unsigned u) { return __uint_as_float(u & 0xFFFF0000u); }

// ---------- Kernel 1 (fused staging): role by blockIdx.x
//   block 0:            counting sort of neurons by base pixel -> perm
//   blocks 1..2048:     pack W [N,CT] f32 -> bf16
//   blocks 2049..12544: transpose+pack x [B,CT,36,36] f32 -> feat [pix][B][CT] bf16
__global__ __launch_bounds__(256) void stage_kernel(
    const float* __restrict__ x, __hip_bfloat16* __restrict__ feat,
    const float* __restrict__ mu, int* __restrict__ perm,
    const float* __restrict__ W, __hip_bfloat16* __restrict__ Wb)
{
    const int bid = blockIdx.x;
    const int t   = threadIdx.x;

    __shared__ int hist[NBINS];
    __shared__ int chunkSum[48];
    __shared__ unsigned short lds[64][34];

    if (bid == 0) {
        for (int i = t; i < NBINS; i += 256) hist[i] = 0;
        __syncthreads();
        int key[16];
#pragma unroll
        for (int j = 0; j < 16; ++j) {
            const int n = t * 16 + j;
            float gx = fminf(fmaxf(mu[2 * n],     -1.f), 1.f);
            float gy = fminf(fmaxf(mu[2 * n + 1], -1.f), 1.f);
            float ix = (gx + 1.f) * (HW * 0.5f) - 0.5f;
            float iy = (gy + 1.f) * (HW * 0.5f) - 0.5f;
            int xi = min(max((int)floorf(ix), 0), HW - 1);
            int yi = min(max((int)floorf(iy), 0), HW - 1);
            key[j] = yi * HW + xi;
            atomicAdd(&hist[key[j]], 1);
        }
        __syncthreads();
        if (t < 41) {
            int s = 0;
            for (int i = 0; i < 32; ++i) {
                int idx = t * 32 + i;
                if (idx < NBINS) s += hist[idx];
            }
            chunkSum[t] = s;
        }
        __syncthreads();
        if (t == 0) {
            int run = 0;
            for (int i = 0; i < 41; ++i) { int v = chunkSum[i]; chunkSum[i] = run; run += v; }
        }
        __syncthreads();
        if (t < 41) {
            int run = chunkSum[t];
            for (int i = 0; i < 32; ++i) {
                int idx = t * 32 + i;
                if (idx < NBINS) { int v = hist[idx]; hist[idx] = run; run += v; }
            }
        }
        __syncthreads();
#pragma unroll
        for (int j = 0; j < 16; ++j) {
            const int n = t * 16 + j;
            const int pos = atomicAdd(&hist[key[j]], 1);
            perm[pos] = n;
        }
        return;
    }

    if (bid <= PACK_BLKS) {
        const size_t i = ((size_t)(bid - 1) * 256 + t) * 2;   // float4 index
        const float4 a = reinterpret_cast<const float4*>(W)[i];
        const float4 b = reinterpret_cast<const float4*>(W)[i + 1];
        unsigned short o[8] = { bfu(a.x), bfu(a.y), bfu(a.z), bfu(a.w),
                                bfu(b.x), bfu(b.y), bfu(b.z), bfu(b.w) };
        reinterpret_cast<uint4*>((unsigned short*)Wb)[((size_t)(bid - 1) * 256 + t)] =
            *reinterpret_cast<uint4*>(o);
        return;
    }

    const int flat   = bid - 1 - PACK_BLKS;
    const int pBase  = (flat % 41) * 32;
    const int ctBase = ((flat / 41) % 16) * 64;
    const int b      = flat / (41 * 16);
    const size_t xb  = (size_t)b * CT * PIX;
    {
        const int r  = t >> 2;
        const int pc = (t & 3) * 8;
        const float* src = x + xb + (size_t)(ctBase + r) * PIX + pBase + pc;
        if (pBase + 32 <= PIX) {
            float4 a = reinterpret_cast<const float4*>(src)[0];
            float4 c = reinterpret_cast<const float4*>(src)[1];
            lds[r][pc + 0] = bfu(a.x); lds[r][pc + 1] = bfu(a.y);
            lds[r][pc + 2] = bfu(a.z); lds[r][pc + 3] = bfu(a.w);
            lds[r][pc + 4] = bfu(c.x); lds[r][pc + 5] = bfu(c.y);
            lds[r][pc + 6] = bfu(c.z); lds[r][pc + 7] = bfu(c.w);
        } else {
#pragma unroll
            for (int i = 0; i < 8; ++i) {
                int p = pBase + pc + i;
                lds[r][pc + i] = (p < PIX) ? bfu(src[i]) : (unsigned short)0;
            }
        }
    }
    __syncthreads();
    const int pr = t >> 3;
    const int cc = (t & 7) * 8;
    if (pBase + pr < PIX) {
        unsigned short o[8];
#pragma unroll
        for (int i = 0; i < 8; ++i) o[i] = lds[cc + i][pr];
        const size_t off = ((size_t)(pBase + pr) * BATCH + b) * CT + ctBase + cc;
        *reinterpret_cast<uint4*>((unsigned short*)feat + off) = *reinterpret_cast<uint4*>(o);
    }
}

// ---------- Kernel 2: readout. Block = 8 sorted-adjacent neurons x 4 batches.
// 32 (neuron,corner) pairs deduped via wave-0 shuffles; clamp+mask instead of
// padding keeps 16 loads in flight without wasted L2 traffic.
__global__ __launch_bounds__(256) void readout_bf16_kernel(
    const __hip_bfloat16* __restrict__ feat,  // [pix][B][CT] bf16
    const float* __restrict__ mu,             // [N,2]
    const __hip_bfloat16* __restrict__ Wb,    // [N,CT] bf16
    const float* __restrict__ bias,           // [N]
    const int* __restrict__ perm,             // [N] pixel-sorted neuron ids
    float* __restrict__ out)                  // [B,N]
{
    const int bid = blockIdx.x;               // 0..2047
    const int xcd = bid & 7;
    const int r   = bid >> 3;                 // 0..255
    const int g   = xcd * 64 + (r >> 2);      // sorted neuron group 0..511
    const int q   = r & 3;                    // batch quad: batches 4q..4q+3
    const int t = threadIdx.x;
    const int c = t & 127;                    // channel-chunk: channels 8c..8c+7
    const int h = t >> 7;                     // batch pair within quad

    const int4 nA = *reinterpret_cast<const int4*>(perm + g * NB);
    const int4 nB = *reinterpret_cast<const int4*>(perm + g * NB + 4);
    const int nid[NB] = { nA.x, nA.y, nA.z, nA.w, nB.x, nB.y, nB.z, nB.w };

    // W fragments: 8 neurons x 8 bf16 channels -> 8 uint4
    uint4 wq[NB];
#pragma unroll
    for (int nb = 0; nb < NB; ++nb)
        wq[nb] = reinterpret_cast<const uint4*>(Wb + (size_t)nid[nb] * CT)[c];

    __shared__ float wmat[32][NB];
    __shared__ int   upix[32];
    __shared__ float uw[32][NB];
    __shared__ int   ucount_s;

    if (t < 32) {
#pragma unroll
        for (int j = 0; j < NB; ++j) wmat[t][j] = 0.f;
    }

    // phase 1 (wave 0, lanes 0..31): pixel + weight per (neuron, corner) pair
    int   mypix = -1;
    float mycw  = 0.f;
    if (t < 32) {
        const int nb = t >> 2, k = t & 3;
        const int n = nid[nb];
        float gx = fminf(fmaxf(mu[2 * n],     -1.f), 1.f);
        float gy = fminf(fmaxf(mu[2 * n + 1], -1.f), 1.f);
        float ix = (gx + 1.f) * (HW * 0.5f) - 0.5f;
        float iy = (gy + 1.f) * (HW * 0.5f) - 0.5f;
        float x0f = floorf(ix), y0f = floorf(iy);
        float wx1 = ix - x0f, wx0 = 1.f - wx1;
        float wy1 = iy - y0f, wy0 = 1.f - wy1;
        int xx = (int)x0f + (k & 1), yy = (int)y0f + (k >> 1);
        bool valid = (xx >= 0) && (xx < HW) && (yy >= 0) && (yy < HW);
        int xi = min(max(xx, 0), HW - 1), yi = min(max(yy, 0), HW - 1);
        mypix = yi * HW + xi;
        mycw  = ((k & 1) ? wx1 : wx0) * ((k >> 1) ? wy1 : wy0) * (valid ? 1.f : 0.f);
    }

    // first-occurrence slot via register shuffles (all lanes execute)
    int myslot = 63;
#pragma unroll
    for (int j = 31; j >= 0; --j) {
        int pj = __shfl(mypix, j, 64);
        if (pj == mypix) myslot = j;
    }
    if (t < 32) atomicAdd(&wmat[myslot][t >> 2], mycw);

    const bool uniq = (t < 32) && (myslot == t);
    const unsigned long long mask = __ballot(uniq);   // wave 0's is the used one
    if (t == 0) ucount_s = __popcll(mask);
    __syncthreads();

    const int U = ucount_s;                            // 1..32
    if (uniq) {
        const int pos = __popcll(mask & ((1ull << t) - 1));
        upix[pos] = mypix;
#pragma unroll
        for (int j = 0; j < NB; ++j) uw[pos][j] = wmat[t][j];
    }
    __syncthreads();

    float acc[NB][2];
#pragma unroll
    for (int nb = 0; nb < NB; ++nb) { acc[nb][0] = 0.f; acc[nb][1] = 0.f; }

    const int b0 = q * BQ + h * 2;
    const unsigned short* fb = (const unsigned short*)feat + (size_t)b0 * CT + (size_t)c * 8;

    for (int u = 0; u < U; u += 8) {
        int   uidx[8];
        float umsk[8];
        int   poff[8];
#pragma unroll
        for (int s = 0; s < 8; ++s) {
            const int idx = u + s;
            umsk[s] = (idx < U) ? 1.f : 0.f;
            uidx[s] = min(idx, U - 1);
            poff[s] = upix[uidx[s]] * BCT;
        }
        uint4 va[8], vb[8];
#pragma unroll
        for (int s = 0; s < 8; ++s) {
            va[s] = *reinterpret_cast<const uint4*>(fb + poff[s]);
            vb[s] = *reinterpret_cast<const uint4*>(fb + poff[s] + CT);
        }
#pragma unroll
        for (int s = 0; s < 8; ++s) {
            const float4 pw0 = *reinterpret_cast<const float4*>(&uw[uidx[s]][0]);
            const float4 pw1 = *reinterpret_cast<const float4*>(&uw[uidx[s]][4]);
            const float pws[NB] = { pw0.x * umsk[s], pw0.y * umsk[s],
                                    pw0.z * umsk[s], pw0.w * umsk[s],
                                    pw1.x * umsk[s], pw1.y * umsk[s],
                                    pw1.z * umsk[s], pw1.w * umsk[s] };
#if HAVE_FDOT2_BF16
#pragma unroll
            for (int nb = 0; nb < NB; ++nb) {
                if (pws[nb] != 0.f) {          // block-uniform branch
                    float d0 = __builtin_amdgcn_fdot2_f32_bf16(as_bf16x2(va[s].x), as_bf16x2(wq[nb].x), 0.f, false);
                    float d1 = __builtin_amdgcn_fdot2_f32_bf16(as_bf16x2(vb[s].x), as_bf16x2(wq[nb].x), 0.f, false);
                    d0 = __builtin_amdgcn_fdot2_f32_bf16(as_bf16x2(va[s].y), as_bf16x2(wq[nb].y), d0, false);
                    d1 = __builtin_amdgcn_fdot2_f32_bf16(as_bf16x2(vb[s].y), as_bf16x2(wq[nb].y), d1, false);
                    d0 = __builtin_amdgcn_fdot2_f32_bf16(as_bf16x2(va[s].z), as_bf16x2(wq[nb].z), d0, false);
                    d1 = __builtin_amdgcn_fdot2_f32_bf16(as_bf16x2(vb[s].z), as_bf16x2(wq[nb].z), d1, false);
                    d0 = __builtin_amdgcn_fdot2_f32_bf16(as_bf16x2(va[s].w), as_bf16x2(wq[nb].w), d0, false);
                    d1 = __builtin_amdgcn_fdot2_f32_bf16(as_bf16x2(vb[s].w), as_bf16x2(wq[nb].w), d1, false);
                    acc[nb][0] = fmaf(pws[nb], d0, acc[nb][0]);
                    acc[nb][1] = fmaf(pws[nb], d1, acc[nb][1]);
                }
            }
#else
            float fa[8] = { bflo(va[s].x), bfhi(va[s].x), bflo(va[s].y), bfhi(va[s].y),
                            bflo(va[s].z), bfhi(va[s].z), bflo(va[s].w), bfhi(va[s].w) };
            float fbv[8] = { bflo(vb[s].x), bfhi(vb[s].x), bflo(vb[s].y), bfhi(vb[s].y),
                             bflo(vb[s].z), bfhi(vb[s].z), bflo(vb[s].w), bfhi(vb[s].w) };
#pragma unroll
            for (int nb = 0; nb < NB; ++nb) {
                if (pws[nb] != 0.f) {
                    float w0 = bflo(wq[nb].x), w1 = bfhi(wq[nb].x);
                    float w2 = bflo(wq[nb].y), w3 = bfhi(wq[nb].y);
                    float w4 = bflo(wq[nb].z), w5 = bfhi(wq[nb].z);
                    float w6 = bflo(wq[nb].w), w7 = bfhi(wq[nb].w);
                    float d0 = fa[0] * w0, d1 = fbv[0] * w0;
                    d0 = fmaf(fa[1], w1, d0); d1 = fmaf(fbv[1], w1, d1);
                    d0 = fmaf(fa[2], w2, d0); d1 = fmaf(fbv[2], w2, d1);
                    d0 = fmaf(fa[3], w3, d0); d1 = fmaf(fbv[3], w3, d1);
                    d0 = fmaf(fa[4], w4, d0); d1 = fmaf(fbv[4], w4, d1);
                    d0 = fmaf(fa[5], w5, d0); d1 = fmaf(fbv[5], w5, d1);
                    d0 = fmaf(fa[6], w6, d0); d1 = fmaf(fbv[6], w6, d1);
                    d0 = fmaf(fa[7], w7, d0); d1 = fmaf(fbv[7], w7, d1);
                    acc[nb][0] = fmaf(pws[nb], d0, acc[nb][0]);
                    acc[nb][1] = fmaf(pws[nb], d1, acc[nb][1]);
                }
            }
#endif
        }
    }

    // reduce 128 channel-chunks per (neuron, batch): wave shuffle then LDS
    __shared__ float red[4][NB][2];
#pragma unroll
    for (int nb = 0; nb < NB; ++nb) {
#pragma unroll
        for (int i = 0; i < 2; ++i) {
            float v = acc[nb][i];
#pragma unroll
            for (int off = 32; off > 0; off >>= 1)
                v += __shfl_down(v, off, 64);
            acc[nb][i] = v;
        }
    }
    const int wave = t >> 6, lane = t & 63;
    if (lane == 0) {
#pragma unroll
        for (int nb = 0; nb < NB; ++nb) {
            red[wave][nb][0] = acc[nb][0];
            red[wave][nb][1] = acc[nb][1];
        }
    }
    __syncthreads();
    if (t < NB * BQ) {                        // 32 outputs
        const int nb = t >> 2, bl = t & 3;
        const int hh = bl >> 1, i = bl & 1;
        float y = red[hh * 2][nb][i] + red[hh * 2 + 1][nb][i] + bias[nid[nb]];
        const int b = q * BQ + bl;
        out[(size_t)b * NNEUR + nid[nb]] = (y > 0.f) ? (y + 1.f) : expf(y);  // elu+1
    }
}

// ---------- fallback: fp32 strided path straight from x (ws too small)
__global__ __launch_bounds__(256) void readout_f32_strided_kernel(
    const float* __restrict__ x,
    const float* __restrict__ mu,
    const float* __restrict__ Wm,
    const float* __restrict__ bias,
    float* __restrict__ out)
{
    const int n = blockIdx.x;
    const int t = threadIdx.x;
    const float4 w4 = reinterpret_cast<const float4*>(Wm + (size_t)n * CT)[t];
    float gx = fminf(fmaxf(mu[2 * n],     -1.f), 1.f);
    float gy = fminf(fmaxf(mu[2 * n + 1], -1.f), 1.f);
    float ix = (gx + 1.f) * (HW * 0.5f) - 0.5f;
    float iy = (gy + 1.f) * (HW * 0.5f) - 0.5f;
    float x0f = floorf(ix), y0f = floorf(iy);
    float wx1 = ix - x0f, wx0 = 1.f - wx1;
    float wy1 = iy - y0f, wy0 = 1.f - wy1;
    int x0 = (int)x0f, y0 = (int)y0f;
    float cw[4]; int cp[4];
#pragma unroll
    for (int k = 0; k < 4; ++k) {
        int xx = x0 + (k & 1), yy = y0 + (k >> 1);
        bool valid = (xx >= 0) && (xx < HW) && (yy >= 0) && (yy < HW);
        int xi = min(max(xx, 0), HW - 1), yi = min(max(yy, 0), HW - 1);
        cp[k] = yi * HW + xi;
        cw[k] = ((k & 1) ? wx1 : wx0) * ((k >> 1) ? wy1 : wy0) * (valid ? 1.f : 0.f);
    }
    float acc[BATCH];
#pragma unroll
    for (int b = 0; b < BATCH; ++b) {
        float s = 0.f;
#pragma unroll
        for (int k = 0; k < 4; ++k) {
            if (cw[k] != 0.f) {
                const float* fp = x + (size_t)b * CT * PIX + cp[k];
                const int c0 = 4 * t;
                s += cw[k] * (fp[(size_t)(c0 + 0) * PIX] * w4.x
                            + fp[(size_t)(c0 + 1) * PIX] * w4.y
                            + fp[(size_t)(c0 + 2) * PIX] * w4.z
                            + fp[(size_t)(c0 + 3) * PIX] * w4.w);
            }
        }
        acc[b] = s;
    }
#pragma unroll
    for (int b = 0; b < BATCH; ++b) {
        float v = acc[b];
#pragma unroll
        for (int off = 32; off > 0; off >>= 1)
            v += __shfl_down(v, off, 64);
        acc[b] = v;
    }
    __shared__ float red[4][BATCH];
    const int wave = t >> 6, lane = t & 63;
    if (lane == 0) {
#pragma unroll
        for (int b = 0; b < BATCH; ++b) red[wave][b] = acc[b];
    }
    __syncthreads();
    if (t < BATCH) {
        float y = red[0][t] + red[1][t] + red[2][t] + red[3][t] + bias[n];
        out[(size_t)t * NNEUR + n] = (y > 0.f) ? (y + 1.f) : expf(y);
    }
}

extern "C" void kernel_launch(void* const* d_in, const int* in_sizes, int n_in,
                              void* d_out, int out_size, void* d_ws, size_t ws_size,
                              hipStream_t stream)
{
    const float* x    = (const float*)d_in[0];
    const float* mu   = (const float*)d_in[1];
    const float* Wm   = (const float*)d_in[3];
    const float* bias = (const float*)d_in[4];
    float* out = (float*)d_out;

    const size_t featBytes = (size_t)BATCH * PIX * CT * sizeof(__hip_bfloat16); // 42.5 MB
    const size_t wBytes    = (size_t)NNEUR * CT * sizeof(__hip_bfloat16);       // 8.4 MB
    const size_t permBytes = (size_t)NNEUR * sizeof(int);                       // 16 KB
    if (ws_size >= featBytes + wBytes + permBytes) {
        __hip_bfloat16* feat = (__hip_bfloat16*)d_ws;
        __hip_bfloat16* Wb   = (__hip_bfloat16*)((char*)d_ws + featBytes);
        int* perm = (int*)((char*)d_ws + featBytes + wBytes);
        stage_kernel<<<STAGE_GRID, 256, 0, stream>>>(x, feat, mu, perm, Wm, Wb);
        readout_bf16_kernel<<<(NNEUR / NB) * (BATCH / BQ), 256, 0, stream>>>(
            feat, mu, Wb, bias, perm, out);
    } else {
        readout_f32_strided_kernel<<<NNEUR, 256, 0, stream>>>(x, mu, Wm, bias, out);
    }
}

// Round 14
// 57.269 us; speedup vs baseline: 1.0316x; 1.0316x over previous
//
#include <hip/hip_runtime.h>
#include <hip/hip_bf16.h>
#include <cmath>

#define CT    1024   // C*T channels
#define PIX   1296   // 36*36 pixels
#define BATCH 16
#define NNEUR 4096
#define HW    36
#define NBINS (HW * HW)
#define NB    4      // neurons per readout block
#define BQ    4      // batches per readout block
#define BCT   (BATCH * CT)   // stride of one pixel in feat

// staging kernel role layout
#define SORT_BLK   1
#define PACK_BLKS  2048                    // 4096*1024 floats / (256 thr * 8)
#define TRAN_BLKS  (41 * 16 * 16)          // 10496
#define STAGE_GRID (SORT_BLK + PACK_BLKS + TRAN_BLKS)

#if defined(__has_builtin)
#  if __has_builtin(__builtin_amdgcn_fdot2_f32_bf16)
#    define HAVE_FDOT2_BF16 1
#  endif
#endif
#ifndef HAVE_FDOT2_BF16
#  define HAVE_FDOT2_BF16 0
#endif

typedef __bf16 bf16x2 __attribute__((ext_vector_type(2)));
__device__ __forceinline__ bf16x2 as_bf16x2(unsigned u) {
    union { unsigned u; bf16x2 v; } cv; cv.u = u; return cv.v;
}
__device__ __forceinline__ unsigned short bfu(float f) {
    __hip_bfloat16 h = __float2bfloat16(f);
    return *reinterpret_cast<unsigned short*>(&h);
}
__device__ __forceinline__ float bflo(unsigned u) { return __uint_as_float(u << 16); }
__device__ __forceinline__ float bfhi(unsigned u) { return __uint_as_float(u & 0xFFFF0000u); }

// ---------- Kernel 1 (fused staging): role by blockIdx.x
//   block 0:            counting sort of neurons by base pixel -> perm
//   blocks 1..2048:     pack W [N,CT] f32 -> bf16 (unsorted)
//   blocks 2049..12544: transpose+pack x [B,CT,36,36] f32 -> feat [pix][B][CT] bf16
// Roles are mutually independent; sort/pack (latency-bound) overlap the
// BW-bound transpose stream instead of serializing after it.
__global__ __launch_bounds__(256) void stage_kernel(
    const float* __restrict__ x, __hip_bfloat16* __restrict__ feat,
    const float* __restrict__ mu, int* __restrict__ perm,
    const float* __restrict__ W, __hip_bfloat16* __restrict__ Wb)
{
    const int bid = blockIdx.x;
    const int t   = threadIdx.x;

    __shared__ int hist[NBINS];
    __shared__ int chunkSum[48];
    __shared__ unsigned short lds[64][34];

    if (bid == 0) {
        // ---- counting sort, 256 threads x 16 neurons ----
        for (int i = t; i < NBINS; i += 256) hist[i] = 0;
        __syncthreads();
        int key[16];
#pragma unroll
        for (int j = 0; j < 16; ++j) {
            const int n = t * 16 + j;
            float gx = fminf(fmaxf(mu[2 * n],     -1.f), 1.f);
            float gy = fminf(fmaxf(mu[2 * n + 1], -1.f), 1.f);
            float ix = (gx + 1.f) * (HW * 0.5f) - 0.5f;
            float iy = (gy + 1.f) * (HW * 0.5f) - 0.5f;
            int xi = min(max((int)floorf(ix), 0), HW - 1);
            int yi = min(max((int)floorf(iy), 0), HW - 1);
            key[j] = yi * HW + xi;
            atomicAdd(&hist[key[j]], 1);
        }
        __syncthreads();
        if (t < 41) {
            int s = 0;
            for (int i = 0; i < 32; ++i) {
                int idx = t * 32 + i;
                if (idx < NBINS) s += hist[idx];
            }
            chunkSum[t] = s;
        }
        __syncthreads();
        if (t == 0) {
            int run = 0;
            for (int i = 0; i < 41; ++i) { int v = chunkSum[i]; chunkSum[i] = run; run += v; }
        }
        __syncthreads();
        if (t < 41) {
            int run = chunkSum[t];
            for (int i = 0; i < 32; ++i) {
                int idx = t * 32 + i;
                if (idx < NBINS) { int v = hist[idx]; hist[idx] = run; run += v; }
            }
        }
        __syncthreads();
#pragma unroll
        for (int j = 0; j < 16; ++j) {
            const int n = t * 16 + j;
            const int pos = atomicAdd(&hist[key[j]], 1);
            perm[pos] = n;
        }
        return;
    }

    if (bid <= PACK_BLKS) {
        // ---- W pack: thread packs 8 floats (2 x float4 -> 1 ushort8) ----
        const size_t i = ((size_t)(bid - 1) * 256 + t) * 2;   // float4 index
        const float4 a = reinterpret_cast<const float4*>(W)[i];
        const float4 b = reinterpret_cast<const float4*>(W)[i + 1];
        unsigned short o[8] = { bfu(a.x), bfu(a.y), bfu(a.z), bfu(a.w),
                                bfu(b.x), bfu(b.y), bfu(b.z), bfu(b.w) };
        reinterpret_cast<uint4*>((unsigned short*)Wb)[((size_t)(bid - 1) * 256 + t)] =
            *reinterpret_cast<uint4*>(o);
        return;
    }

    // ---- transpose: flat index -> (pBase, ctBase, b) ----
    const int flat   = bid - 1 - PACK_BLKS;
    const int pBase  = (flat % 41) * 32;
    const int ctBase = ((flat / 41) % 16) * 64;
    const int b      = flat / (41 * 16);
    const size_t xb  = (size_t)b * CT * PIX;
    {
        const int r  = t >> 2;
        const int pc = (t & 3) * 8;
        const float* src = x + xb + (size_t)(ctBase + r) * PIX + pBase + pc;
        if (pBase + 32 <= PIX) {
            float4 a = reinterpret_cast<const float4*>(src)[0];
            float4 c = reinterpret_cast<const float4*>(src)[1];
            lds[r][pc + 0] = bfu(a.x); lds[r][pc + 1] = bfu(a.y);
            lds[r][pc + 2] = bfu(a.z); lds[r][pc + 3] = bfu(a.w);
            lds[r][pc + 4] = bfu(c.x); lds[r][pc + 5] = bfu(c.y);
            lds[r][pc + 6] = bfu(c.z); lds[r][pc + 7] = bfu(c.w);
        } else {
#pragma unroll
            for (int i = 0; i < 8; ++i) {
                int p = pBase + pc + i;
                lds[r][pc + i] = (p < PIX) ? bfu(src[i]) : (unsigned short)0;
            }
        }
    }
    __syncthreads();
    const int pr = t >> 3;
    const int cc = (t & 7) * 8;
    if (pBase + pr < PIX) {
        unsigned short o[8];
#pragma unroll
        for (int i = 0; i < 8; ++i) o[i] = lds[cc + i][pr];
        const size_t off = ((size_t)(pBase + pr) * BATCH + b) * CT + ctBase + cc;
        *reinterpret_cast<uint4*>((unsigned short*)feat + off) = *reinterpret_cast<uint4*>(o);
    }
}

// ---------- Kernel 2: readout. Block = 4 sorted-adjacent neurons x 4 batches.
// Dedupe via wave shuffles + ballot; u-loop padded to multiple of 8 so the
// whole pixel loop is 1-2 bursts of 16 in-flight 16B loads. fdot2 hot loop.
__global__ __launch_bounds__(256, 4) void readout_bf16_kernel(
    const __hip_bfloat16* __restrict__ feat,  // [pix][B][CT] bf16
    const float* __restrict__ mu,             // [N,2]
    const __hip_bfloat16* __restrict__ Wb,    // [N,CT] bf16
    const float* __restrict__ bias,           // [N]
    const int* __restrict__ perm,             // [N] pixel-sorted neuron ids
    float* __restrict__ out)                  // [B,N]
{
    const int bid = blockIdx.x;               // 0..4095
    const int xcd = bid & 7;
    const int r   = bid >> 3;                 // 0..511
    const int g   = xcd * 128 + (r >> 2);     // sorted neuron group 0..1023
    const int q   = r & 3;                    // batch quad: batches 4q..4q+3
    const int t = threadIdx.x;
    const int c = t & 127;                    // channel-chunk: channels 8c..8c+7
    const int h = t >> 7;                     // batch pair within quad

    const int4 nids = *reinterpret_cast<const int4*>(perm + g * NB);
    const int nid[NB] = { nids.x, nids.y, nids.z, nids.w };

    // W fragments: 4 neurons x 8 bf16 channels -> 4 uint4
    uint4 wq[NB];
#pragma unroll
    for (int nb = 0; nb < NB; ++nb)
        wq[nb] = reinterpret_cast<const uint4*>(Wb + (size_t)nid[nb] * CT)[c];

#if !HAVE_FDOT2_BF16
    float w[NB][8];
#pragma unroll
    for (int nb = 0; nb < NB; ++nb) {
        w[nb][0] = bflo(wq[nb].x); w[nb][1] = bfhi(wq[nb].x);
        w[nb][2] = bflo(wq[nb].y); w[nb][3] = bfhi(wq[nb].y);
        w[nb][4] = bflo(wq[nb].z); w[nb][5] = bfhi(wq[nb].z);
        w[nb][6] = bflo(wq[nb].w); w[nb][7] = bfhi(wq[nb].w);
    }
#endif

    __shared__ float wmat16[16][NB];
    __shared__ int   upix[16];
    __shared__ float uw[16][NB];
    __shared__ int   ucount_s;

    if (t < 16) {
#pragma unroll
        for (int j = 0; j < NB; ++j) wmat16[t][j] = 0.f;
    }

    // phase 1 (wave 0): pixel + weight per (neuron, corner) pair, in registers
    int   mypix = -1;
    float mycw  = 0.f;
    if (t < 16) {
        const int nb = t >> 2, k = t & 3;
        const int n = nid[nb];
        float gx = fminf(fmaxf(mu[2 * n],     -1.f), 1.f);
        float gy = fminf(fmaxf(mu[2 * n + 1], -1.f), 1.f);
        float ix = (gx + 1.f) * (HW * 0.5f) - 0.5f;
        float iy = (gy + 1.f) * (HW * 0.5f) - 0.5f;
        float x0f = floorf(ix), y0f = floorf(iy);
        float wx1 = ix - x0f, wx0 = 1.f - wx1;
        float wy1 = iy - y0f, wy0 = 1.f - wy1;
        int xx = (int)x0f + (k & 1), yy = (int)y0f + (k >> 1);
        bool valid = (xx >= 0) && (xx < HW) && (yy >= 0) && (yy < HW);
        int xi = min(max(xx, 0), HW - 1), yi = min(max(yy, 0), HW - 1);
        mypix = yi * HW + xi;
        mycw  = ((k & 1) ? wx1 : wx0) * ((k >> 1) ? wy1 : wy0) * (valid ? 1.f : 0.f);
    }

    // first-occurrence slot via register shuffles (all lanes execute)
    int myslot = 15;
#pragma unroll
    for (int j = 15; j >= 0; --j) {
        int pj = __shfl(mypix, j, 64);
        if (pj == mypix) myslot = j;
    }
    if (t < 16) atomicAdd(&wmat16[myslot][t >> 2], mycw);

    const bool uniq = (t < 16) && (myslot == t);
    const unsigned long long mask = __ballot(uniq);   // wave 0's is the used one
    if (t == 0) ucount_s = __popcll(mask);
    const int pix0 = __shfl(mypix, 0, 64);            // pad pixel (valid in wave 0)
    __syncthreads();

    const int U    = ucount_s;
    const int Upad = (U + 7) & ~7;                    // 8 or 16
    if (uniq) {
        const int pos = __popcll(mask & ((1ull << t) - 1));
        upix[pos] = mypix;
#pragma unroll
        for (int j = 0; j < NB; ++j) uw[pos][j] = wmat16[t][j];
    }
    if (t >= U && t < Upad) {                          // zero-weight padding
        upix[t] = pix0;
#pragma unroll
        for (int j = 0; j < NB; ++j) uw[t][j] = 0.f;
    }
    __syncthreads();

    float acc[NB][2];
#pragma unroll
    for (int nb = 0; nb < NB; ++nb) { acc[nb][0] = 0.f; acc[nb][1] = 0.f; }

    const int b0 = q * BQ + h * 2;
    const unsigned short* fb = (const unsigned short*)feat + (size_t)b0 * CT + (size_t)c * 8;

    for (int u = 0; u < Upad; u += 8) {
        int poff[8];
#pragma unroll
        for (int s = 0; s < 8; ++s) poff[s] = upix[u + s] * BCT;
        uint4 va[8], vb[8];
#pragma unroll
        for (int s = 0; s < 8; ++s) {
            va[s] = *reinterpret_cast<const uint4*>(fb + poff[s]);
            vb[s] = *reinterpret_cast<const uint4*>(fb + poff[s] + CT);
        }
#pragma unroll
        for (int s = 0; s < 8; ++s) {
            const float4 pw = *reinterpret_cast<const float4*>(uw[u + s]);
            const float pws[NB] = { pw.x, pw.y, pw.z, pw.w };
#if HAVE_FDOT2_BF16
#pragma unroll
            for (int nb = 0; nb < NB; ++nb) {
                if (pws[nb] != 0.f) {          // block-uniform branch
                    float d0 = __builtin_amdgcn_fdot2_f32_bf16(as_bf16x2(va[s].x), as_bf16x2(wq[nb].x), 0.f, false);
                    float d1 = __builtin_amdgcn_fdot2_f32_bf16(as_bf16x2(vb[s].x), as_bf16x2(wq[nb].x), 0.f, false);
                    d0 = __builtin_amdgcn_fdot2_f32_bf16(as_bf16x2(va[s].y), as_bf16x2(wq[nb].y), d0, false);
                    d1 = __builtin_amdgcn_fdot2_f32_bf16(as_bf16x2(vb[s].y), as_bf16x2(wq[nb].y), d1, false);
                    d0 = __builtin_amdgcn_fdot2_f32_bf16(as_bf16x2(va[s].z), as_bf16x2(wq[nb].z), d0, false);
                    d1 = __builtin_amdgcn_fdot2_f32_bf16(as_bf16x2(vb[s].z), as_bf16x2(wq[nb].z), d1, false);
                    d0 = __builtin_amdgcn_fdot2_f32_bf16(as_bf16x2(va[s].w), as_bf16x2(wq[nb].w), d0, false);
                    d1 = __builtin_amdgcn_fdot2_f32_bf16(as_bf16x2(vb[s].w), as_bf16x2(wq[nb].w), d1, false);
                    acc[nb][0] = fmaf(pws[nb], d0, acc[nb][0]);
                    acc[nb][1] = fmaf(pws[nb], d1, acc[nb][1]);
                }
            }
#else
            float fa[8] = { bflo(va[s].x), bfhi(va[s].x), bflo(va[s].y), bfhi(va[s].y),
                            bflo(va[s].z), bfhi(va[s].z), bflo(va[s].w), bfhi(va[s].w) };
            float fbv[8] = { bflo(vb[s].x), bfhi(vb[s].x), bflo(vb[s].y), bfhi(vb[s].y),
                             bflo(vb[s].z), bfhi(vb[s].z), bflo(vb[s].w), bfhi(vb[s].w) };
#pragma unroll
            for (int nb = 0; nb < NB; ++nb) {
                if (pws[nb] != 0.f) {
                    float d0 = fa[0]  * w[nb][0];
                    float d1 = fbv[0] * w[nb][0];
#pragma unroll
                    for (int j = 1; j < 8; ++j) {
                        d0 = fmaf(fa[j],  w[nb][j], d0);
                        d1 = fmaf(fbv[j], w[nb][j], d1);
                    }
                    acc[nb][0] = fmaf(pws[nb], d0, acc[nb][0]);
                    acc[nb][1] = fmaf(pws[nb], d1, acc[nb][1]);
                }
            }
#endif
        }
    }

    // reduce 128 channel-chunks per (neuron, batch): wave shuffle then LDS
    __shared__ float red[4][NB][2];
#pragma unroll
    for (int nb = 0; nb < NB; ++nb) {
#pragma unroll
        for (int i = 0; i < 2; ++i) {
            float v = acc[nb][i];
#pragma unroll
            for (int off = 32; off > 0; off >>= 1)
                v += __shfl_down(v, off, 64);
            acc[nb][i] = v;
        }
    }
    const int wave = t >> 6, lane = t & 63;
    if (lane == 0) {
#pragma unroll
        for (int nb = 0; nb < NB; ++nb) {
            red[wave][nb][0] = acc[nb][0];
            red[wave][nb][1] = acc[nb][1];
        }
    }
    __syncthreads();
    if (t < NB * BQ) {                        // 16 outputs
        const int nb = t >> 2, bl = t & 3;
        const int hh = bl >> 1, i = bl & 1;
        float y = red[hh * 2][nb][i] + red[hh * 2 + 1][nb][i] + bias[nid[nb]];
        const int b = q * BQ + bl;
        out[(size_t)b * NNEUR + nid[nb]] = (y > 0.f) ? (y + 1.f) : expf(y);  // elu+1
    }
}

// ---------- fallback: fp32 strided path straight from x (ws too small)
__global__ __launch_bounds__(256) void readout_f32_strided_kernel(
    const float* __restrict__ x,
    const float* __restrict__ mu,
    const float* __restrict__ Wm,
    const float* __restrict__ bias,
    float* __restrict__ out)
{
    const int n = blockIdx.x;
    const int t = threadIdx.x;
    const float4 w4 = reinterpret_cast<const float4*>(Wm + (size_t)n * CT)[t];
    float gx = fminf(fmaxf(mu[2 * n],     -1.f), 1.f);
    float gy = fminf(fmaxf(mu[2 * n + 1], -1.f), 1.f);
    float ix = (gx + 1.f) * (HW * 0.5f) - 0.5f;
    float iy = (gy + 1.f) * (HW * 0.5f) - 0.5f;
    float x0f = floorf(ix), y0f = floorf(iy);
    float wx1 = ix - x0f, wx0 = 1.f - wx1;
    float wy1 = iy - y0f, wy0 = 1.f - wy1;
    int x0 = (int)x0f, y0 = (int)y0f;
    float cw[4]; int cp[4];
#pragma unroll
    for (int k = 0; k < 4; ++k) {
        int xx = x0 + (k & 1), yy = y0 + (k >> 1);
        bool valid = (xx >= 0) && (xx < HW) && (yy >= 0) && (yy < HW);
        int xi = min(max(xx, 0), HW - 1), yi = min(max(yy, 0), HW - 1);
        cp[k] = yi * HW + xi;
        cw[k] = ((k & 1) ? wx1 : wx0) * ((k >> 1) ? wy1 : wy0) * (valid ? 1.f : 0.f);
    }
    float acc[BATCH];
#pragma unroll
    for (int b = 0; b < BATCH; ++b) {
        float s = 0.f;
#pragma unroll
        for (int k = 0; k < 4; ++k) {
            if (cw[k] != 0.f) {
                const float* fp = x + (size_t)b * CT * PIX + cp[k];
                const int c0 = 4 * t;
                s += cw[k] * (fp[(size_t)(c0 + 0) * PIX] * w4.x
                            + fp[(size_t)(c0 + 1) * PIX] * w4.y
                            + fp[(size_t)(c0 + 2) * PIX] * w4.z
                            + fp[(size_t)(c0 + 3) * PIX] * w4.w);
            }
        }
        acc[b] = s;
    }
#pragma unroll
    for (int b = 0; b < BATCH; ++b) {
        float v = acc[b];
#pragma unroll
        for (int off = 32; off > 0; off >>= 1)
            v += __shfl_down(v, off, 64);
        acc[b] = v;
    }
    __shared__ float red[4][BATCH];
    const int wave = t >> 6, lane = t & 63;
    if (lane == 0) {
#pragma unroll
        for (int b = 0; b < BATCH; ++b) red[wave][b] = acc[b];
    }
    __syncthreads();
    if (t < BATCH) {
        float y = red[0][t] + red[1][t] + red[2][t] + red[3][t] + bias[n];
        out[(size_t)t * NNEUR + n] = (y > 0.f) ? (y + 1.f) : expf(y);
    }
}

extern "C" void kernel_launch(void* const* d_in, const int* in_sizes, int n_in,
                              void* d_out, int out_size, void* d_ws, size_t ws_size,
                              hipStream_t stream)
{
    const float* x    = (const float*)d_in[0];
    const float* mu   = (const float*)d_in[1];
    const float* Wm   = (const float*)d_in[3];
    const float* bias = (const float*)d_in[4];
    float* out = (float*)d_out;

    const size_t featBytes = (size_t)BATCH * PIX * CT * sizeof(__hip_bfloat16); // 42.5 MB
    const size_t wBytes    = (size_t)NNEUR * CT * sizeof(__hip_bfloat16);       // 8.4 MB
    const size_t permBytes = (size_t)NNEUR * sizeof(int);                       // 16 KB
    if (ws_size >= featBytes + wBytes + permBytes) {
        __hip_bfloat16* feat = (__hip_bfloat16*)d_ws;
        __hip_bfloat16* Wb   = (__hip_bfloat16*)((char*)d_ws + featBytes);
        int* perm = (int*)((char*)d_ws + featBytes + wBytes);
        stage_kernel<<<STAGE_GRID, 256, 0, stream>>>(x, feat, mu, perm, Wm, Wb);
        readout_bf16_kernel<<<(NNEUR / NB) * (BATCH / BQ), 256, 0, stream>>>(
            feat, mu, Wb, bias, perm, out);
    } else {
        readout_f32_strided_kernel<<<NNEUR, 256, 0, stream>>>(x, mu, Wm, bias, out);
    }
}